// Round 22
// baseline (375.597 us; speedup 1.0000x reference)
//
#include <hip/hip_runtime.h>
#include <hip/hip_fp16.h>
#include <cstdint>
#include <cstddef>

#define D       512
#define NROWS   16384
#define NCODES  8192
#define BM      128
#define BN      128
#define NKC     16              // phases: BK=32 each
#define NBLK    8192            // (16384/128)*(8192/128)
#define EPS     0.2f            // 2B; fp16 1-term err std ~0.03 -> ~6.5 sigma
#define TCB     2048            // tail kernel blocks (8 rows each)
#define TILE_B  8192            // packed fp16 tile per (blk128, ktile32)
#define NCH     128             // 64-code chunks per row

typedef __attribute__((ext_vector_type(8))) short short8;  // 8 fp16
typedef __attribute__((ext_vector_type(4))) float f32x4;
typedef unsigned long long u64;

// order-preserving fp32 <-> u32 key
__device__ __forceinline__ uint32_t fkey(float f) {
  uint32_t u = __float_as_uint(f);
  return (u & 0x80000000u) ? ~u : (u | 0x80000000u);
}
__device__ __forceinline__ float unfkey(uint32_t k) {
  uint32_t u = (k & 0x80000000u) ? (k & 0x7FFFFFFFu) : ~k;
  return __uint_as_float(u);
}
__device__ __forceinline__ uint32_t pkh(float a, float b) {  // 2xfp16 RN pack
  const uint32_t ua = (uint32_t)__half_as_ushort(__float2half(a));
  const uint32_t ub = (uint32_t)__half_as_ushort(__float2half(b));
  return ua | (ub << 16);
}

// ---------------------------------------------------------------------------
// Pre-pack fp32 -> fp16, OUTPUT-address-ordered, tile-kc layout, plus fused
// workspace init (min1/min2/loss).  Chunk (r, cp) at byte r*64 + cp*16
// within an 8KB tile; cp = c ^ ((r>>1)&3).
// ---------------------------------------------------------------------------
__global__ __launch_bounds__(256) void vq_pack_kernel(
    const float* __restrict__ x, const float* __restrict__ embed,
    uint32_t* __restrict__ px, uint32_t* __restrict__ pe,
    u64* __restrict__ min1g, u64* __restrict__ min2g,
    float* __restrict__ out_loss) {
  const int oid  = blockIdx.x * 256 + threadIdx.x;
  const bool isX = oid < NROWS * 64;        // block-uniform split
  const int tt   = isX ? oid : oid - NROWS * 64;
  const float* src = isX ? x : embed;
  uint32_t*    dst = isX ? px : pe;

  if (oid < NROWS) { min1g[oid] = ~0ull; min2g[oid] = ~0ull; }
  if (oid == 0) *out_loss = 0.f;

  const int tile   = tt >> 9;        // (blk,kc): 512 chunks each
  const int within = tt & 511;       // = r*4 + cp
  const int blk = tile >> 4, kc = tile & 15;
  const int r   = within >> 2, cpp = within & 3;
  const int c   = cpp ^ ((r >> 1) & 3);     // source k-quarter

  const float* sp = src + (size_t)(blk * 128 + r) * D + kc * 32 + c * 8;
  const float4 v0 = *(const float4*)sp;
  const float4 v1 = *(const float4*)(sp + 4);
  uint32_t* dp = dst + (size_t)tile * 2048 + within * 4;
  *(uint4*)dp = make_uint4(pkh(v0.x, v0.y), pkh(v0.z, v0.w),
                           pkh(v1.x, v1.y), pkh(v1.z, v1.w));
}

// ---------------------------------------------------------------------------
__global__ void vq_e2_kernel(const float* __restrict__ embed,
                             float* __restrict__ e2) {
  const int w    = (blockIdx.x * blockDim.x + threadIdx.x) >> 6;
  const int lane = threadIdx.x & 63;
  const float* p = embed + (size_t)w * D + lane * 8;
  const float4 a = *(const float4*)p;
  const float4 b = *(const float4*)(p + 4);
  float s = a.x * a.x + a.y * a.y + a.z * a.z + a.w * a.w +
            b.x * b.x + b.y * b.y + b.z * b.z + b.w * b.w;
#pragma unroll
  for (int m = 32; m >= 1; m >>= 1) s += __shfl_xor(s, m, 64);
  if (lane == 0) e2[w] = s;
}

// ---------------------------------------------------------------------------
// MFMA distance kernel, BARRIER-FREE main loop: fragments loaded DIRECTLY
// global->VGPR from the packed (frag-shaped, L2-resident) tiles — no LDS
// staging at all.  R21 diagnosis: phase barriers lockstepped all resident
// waves -> LDS-read burst (~1300cyc) alternated with MFMA burst (~1040cyc),
// each pipe idle while the other drained (28% MfmaUtil, all pipes <40%).
// Desynced waves overlap those phases naturally; per-wave ILP + 4 waves/SIMD
// hide L2 latency.  A wave's 64 lanes read each 1KB frag region bijectively
// (coalesced); address math identical to the LDS path, re-based to global.
// ---------------------------------------------------------------------------
__global__ __launch_bounds__(256, 4) void vq_mfma_kernel(
    const uint32_t* __restrict__ xp, const uint32_t* __restrict__ ep,
    const float* __restrict__ e2g, u64* __restrict__ min1g,
    u64* __restrict__ min2g, float* __restrict__ chunkmin) {
  __shared__ u64 mb[BM][2][2];   // epilogue merge only (4 KB)

  const int tid  = threadIdx.x;
  const int lane = tid & 63;
  const int w    = tid >> 6;          // 0..3
  const int wr   = (w >> 1) * 64;
  const int wcI  = w & 1;
  const int wc   = wcI * 64;

  // XCD swizzle (8192 % 8 == 0 -> bijective); cb fast-varying for L2 reuse.
  const int xcd = blockIdx.x & 7;
  const int id  = blockIdx.x >> 3;     // 0..1023
  const int cb  = xcd * 8 + (id & 7);  // 0..63
  const int rb  = id >> 3;             // 0..127
  const int row0 = rb * BM;
  const int c0   = cb * BN;

  const char* xtile = (const char*)xp + (size_t)rb * (NKC * TILE_B);
  const char* etile = (const char*)ep + (size_t)cb * (NKC * TILE_B);

  f32x4 acc[4][4];
#pragma unroll
  for (int i = 0; i < 4; ++i)
#pragma unroll
    for (int j = 0; j < 4; ++j) acc[i][j] = (f32x4)0.f;

  const int fr = lane & 15;
  const int cl = lane >> 4;
  const int cs = (cl ^ ((fr >> 1) & 3)) * 16;  // swizzle baked into pack

  for (int kc = 0; kc < NKC; ++kc) {
    const char* gx = xtile + (size_t)kc * TILE_B;
    const char* ge = etile + (size_t)kc * TILE_B;
    short8 bh[4];
#pragma unroll
    for (int j = 0; j < 4; ++j) {
      const int erow = wc + j * 16 + fr;
      bh[j] = *(const short8*)(ge + erow * 64 + cs);
    }
#pragma unroll
    for (int i = 0; i < 4; ++i) {
      const int arow = wr + i * 16 + fr;
      const short8 ah = *(const short8*)(gx + arow * 64 + cs);
      __builtin_amdgcn_s_setprio(1);
#pragma unroll
      for (int j = 0; j < 4; ++j)
        acc[i][j] = __builtin_amdgcn_mfma_f32_16x16x32_f16(ah, bh[j], acc[i][j], 0, 0, 0);
      __builtin_amdgcn_s_setprio(0);
    }
  }

  // ---- epilogue: per-row top-2 over this block's 128 codes ----
  float e2v[4];
#pragma unroll
  for (int j = 0; j < 4; ++j) e2v[j] = e2g[c0 + wc + j * 16 + fr];

#pragma unroll
  for (int i = 0; i < 4; ++i) {
#pragma unroll
    for (int r = 0; r < 4; ++r) {
      float v1 = 3.4e38f, v2 = 3.4e38f;
      int c1 = 0;
#pragma unroll
      for (int j = 0; j < 4; ++j) {   // codes ascend with j: lowest-idx ties
        const float s = fmaf(-2.f, acc[i][j][r], e2v[j]);
        if (s < v1) { v2 = v1; v1 = s; c1 = c0 + wc + j * 16 + fr; }
        else if (s < v2) v2 = s;
      }
      u64 p1 = ((u64)fkey(v1) << 32) | (uint32_t)c1;
      uint32_t k2 = fkey(v2);
#pragma unroll
      for (int m = 8; m >= 1; m >>= 1) {   // merge across 16-lane row-group
        const u64 o1 = __shfl_xor(p1, m, 64);
        const uint32_t o2 = __shfl_xor(k2, m, 64);
        const u64 lo_ = p1 < o1 ? p1 : o1;
        const u64 hi_ = p1 < o1 ? o1 : p1;
        uint32_t nk = k2 < o2 ? k2 : o2;
        const uint32_t hk = (uint32_t)(hi_ >> 32);
        k2 = nk < hk ? nk : hk;
        p1 = lo_;
      }
      if ((lane & 15) == 0) {
        const int lrow = wr + i * 16 + (lane >> 4) * 4 + r;
        mb[lrow][wcI][0] = p1;
        mb[lrow][wcI][1] = ((u64)k2 << 32) | 0xFFFFFFFFull;
      }
    }
  }
  __syncthreads();

  if (tid < BM) {
    const u64 m1a = mb[tid][0][0], m2a = mb[tid][0][1];
    const u64 m1b = mb[tid][1][0], m2b = mb[tid][1][1];
    // chunkmin at 64-code granularity, coalesced [chunk][row] layout
    chunkmin[(size_t)(cb * 2 + 0) * NROWS + row0 + tid] =
        unfkey((uint32_t)(m1a >> 32));
    chunkmin[(size_t)(cb * 2 + 1) * NROWS + row0 + tid] =
        unfkey((uint32_t)(m1b >> 32));
    const u64 m1 = m1a < m1b ? m1a : m1b;
    const u64 big = m1a < m1b ? m1b : m1a;
    u64 m2 = m2a < m2b ? m2a : m2b;
    m2 = m2 < big ? m2 : big;
    // lock-free global top-2 merge
    const u64 old = atomicMin(&min1g[row0 + tid], m1);
    u64 push = m1 < old ? old : m1;       // max(m1, old)
    push = m2 < push ? m2 : push;
    atomicMin(&min2g[row0 + tid], push);
  }
}

// ---------------------------------------------------------------------------
// Fused tail: flag + targeted exact rescan + gather/idx/loss finish.
// Block owns 8 rows; loss reduced to ONE atomicAdd per block (R21 fix:
// 16384 same-address atomics serialized at ~300us with all pipes idle).
// ---------------------------------------------------------------------------
__global__ __launch_bounds__(256) void vq_tail_kernel(
    const float* __restrict__ x, const float* __restrict__ embed,
    const float* __restrict__ e2g, const float* __restrict__ chunkmin,
    const u64* __restrict__ min1g, const u64* __restrict__ min2g,
    float* __restrict__ out_q, float* __restrict__ out_idx,
    float* __restrict__ out_loss) {
  __shared__ u64 rowres[8];
  __shared__ u64 wbest[4];
  __shared__ float lsh[4];
  const int lane = threadIdx.x & 63;
  const int wv   = threadIdx.x >> 6;
  const int row0 = blockIdx.x * 8;

  if (threadIdx.x < 8) rowres[threadIdx.x] = min1g[row0 + threadIdx.x];
  __syncthreads();

  // ---- phase A: rescan flagged rows (gap test is block-uniform) ----
  for (int r = 0; r < 8; ++r) {
    const int row = row0 + r;
    const float f1 = unfkey((uint32_t)(rowres[r] >> 32));
    const float f2 = unfkey((uint32_t)(min2g[row] >> 32));
    if (f2 - f1 >= EPS) continue;       // NaN -> rescan
    const float thr = f1 + EPS;

    const float* xpr = x + (size_t)row * D + lane * 8;
    const float4 xa = *(const float4*)xpr;
    const float4 xb = *(const float4*)(xpr + 4);

    float bv = 3.4e38f;
    int   bi = 0x7FFFFFFF;
    for (int g = wv; g < NCH; g += 4) {
      if (chunkmin[(size_t)g * NROWS + row] > thr) continue;  // wave-uniform
      const int cbase = g * 64;
      for (int i = 0; i < 64; ++i) {
        const int c = cbase + i;
        const float* epr = embed + (size_t)c * D + lane * 8;
        const float4 ea = *(const float4*)epr;
        const float4 eb = *(const float4*)(epr + 4);
        float p = xa.x * ea.x + xa.y * ea.y + xa.z * ea.z + xa.w * ea.w +
                  xb.x * eb.x + xb.y * eb.y + xb.z * eb.z + xb.w * eb.w;
#pragma unroll
        for (int m = 32; m >= 1; m >>= 1) p += __shfl_xor(p, m, 64);
        const float s = fmaf(-2.f, p, e2g[c]);
        if (s < bv || (s == bv && c < bi)) { bv = s; bi = c; }
      }
    }
    const u64 pk = ((u64)fkey(bv) << 32) | (uint32_t)bi;
    if (lane == 0) wbest[wv] = pk;
    __syncthreads();
    if (threadIdx.x == 0) {
      u64 m = wbest[0];
#pragma unroll
      for (int q = 1; q < 4; ++q) m = wbest[q] < m ? wbest[q] : m;
      rowres[r] = m;   // exact result REPLACES approx (R10 lesson)
    }
    __syncthreads();
  }
  __syncthreads();

  // ---- phase B: finish (gather winning row, idx); loss in registers ----
  float lacc = 0.f;
  for (int rr = wv; rr < 8; rr += 4) {
    const int row = row0 + rr;
    const int idx = (int)(rowres[rr] & 0xFFFFFFFFull);
    if (lane == 0) out_idx[row] = (float)idx;

    const float* ep = embed + (size_t)idx * D + lane * 8;
    const float* xp = x + (size_t)row * D + lane * 8;
    float* qp       = out_q + (size_t)row * D + lane * 8;

    const float4 e0 = *(const float4*)ep;
    const float4 e1 = *(const float4*)(ep + 4);
    const float4 x0 = *(const float4*)xp;
    const float4 x1 = *(const float4*)(xp + 4);
    *(float4*)qp       = e0;   // x + sg(q - x) == q numerically
    *(float4*)(qp + 4) = e1;

    lacc += (e0.x - x0.x) * (e0.x - x0.x) + (e0.y - x0.y) * (e0.y - x0.y) +
            (e0.z - x0.z) * (e0.z - x0.z) + (e0.w - x0.w) * (e0.w - x0.w) +
            (e1.x - x1.x) * (e1.x - x1.x) + (e1.y - x1.y) * (e1.y - x1.y) +
            (e1.z - x1.z) * (e1.z - x1.z) + (e1.w - x1.w) * (e1.w - x1.w);
  }
  // one butterfly per wave, cross-wave via LDS, ONE atomic per block
#pragma unroll
  for (int m = 32; m >= 1; m >>= 1) lacc += __shfl_xor(lacc, m, 64);
  if (lane == 0) lsh[wv] = lacc;
  __syncthreads();
  if (threadIdx.x == 0) {
    const float t = lsh[0] + lsh[1] + lsh[2] + lsh[3];
    atomicAdd(out_loss, t * (1.f / (float)((size_t)NROWS * D)));
  }
}

// ---------------------------------------------------------------------------
extern "C" void kernel_launch(void* const* d_in, const int* in_sizes, int n_in,
                              void* d_out, int out_size, void* d_ws,
                              size_t ws_size, hipStream_t stream) {
  (void)in_sizes; (void)n_in; (void)out_size; (void)ws_size;
  const float* x     = (const float*)d_in[0];
  const float* embed = (const float*)d_in[1];

  char* ws = (char*)d_ws;
  u64*  min1    = (u64*)ws;                                  // 128 KB
  u64*  min2    = (u64*)(ws + (size_t)NROWS * 8);            // 128 KB
  float* e2     = (float*)(ws + (size_t)NROWS * 16);         // 32 KB
  float* chkmin = (float*)(ws + (1u << 20));                 // 8 MB @ 1 MB
  uint32_t* pack_x = (uint32_t*)(ws + (10u << 20));          // 16 MB @ 10 MB
  uint32_t* pack_e = (uint32_t*)(ws + (26u << 20));          // 8 MB @ 26 MB

  float* out_q    = (float*)d_out;                 // [16384][512]
  float* out_idx  = out_q + (size_t)NROWS * D;     // [16384] as float
  float* out_loss = out_idx + NROWS;               // [1]

  // 4 dispatches
  vq_pack_kernel<<<(NROWS + NCODES) * 64 / 256, 256, 0, stream>>>(
      x, embed, pack_x, pack_e, min1, min2, out_loss);
  vq_e2_kernel<<<NCODES / 4, 256, 0, stream>>>(embed, e2);
  vq_mfma_kernel<<<NBLK, 256, 0, stream>>>(pack_x, pack_e, e2, min1, min2,
                                           chkmin);
  vq_tail_kernel<<<TCB, 256, 0, stream>>>(x, embed, e2, chkmin, min1, min2,
                                          out_q, out_idx, out_loss);
}

// Round 23
// 356.338 us; speedup vs baseline: 1.0540x; 1.0540x over previous
//
#include <hip/hip_runtime.h>
#include <hip/hip_fp16.h>
#include <cstdint>
#include <cstddef>

#define D       512
#define NROWS   16384
#define NCODES  8192
#define BM      128
#define BN      128
#define NKC     16              // phases: BK=32 each
#define NBLK    8192            // (16384/128)*(8192/128)
#define EPS     0.2f            // 2B; fp16 1-term err std ~0.03 -> ~6.5 sigma
#define TCB     2048            // tail kernel blocks (8 rows each)
#define TILE_B  8192            // packed fp16 tile per (blk128, ktile32)
#define NCH     128             // 64-code chunks per row
#define NSLOT   32              // loss fan-out slots

typedef __attribute__((ext_vector_type(8))) short short8;  // 8 fp16
typedef __attribute__((ext_vector_type(4))) float f32x4;
typedef unsigned long long u64;
typedef __attribute__((address_space(3))) uint32_t as3_u32;
typedef __attribute__((address_space(1))) uint32_t as1_u32;

// order-preserving fp32 <-> u32 key
__device__ __forceinline__ uint32_t fkey(float f) {
  uint32_t u = __float_as_uint(f);
  return (u & 0x80000000u) ? ~u : (u | 0x80000000u);
}
__device__ __forceinline__ float unfkey(uint32_t k) {
  uint32_t u = (k & 0x80000000u) ? (k & 0x7FFFFFFFu) : ~k;
  return __uint_as_float(u);
}
__device__ __forceinline__ uint32_t pkh(float a, float b) {  // 2xfp16 RN pack
  const uint32_t ua = (uint32_t)__half_as_ushort(__float2half(a));
  const uint32_t ub = (uint32_t)__half_as_ushort(__float2half(b));
  return ua | (ub << 16);
}

// ---------------------------------------------------------------------------
// Pre-pack fp32 -> fp16, OUTPUT-address-ordered, tile-kc layout, plus fused
// workspace init (min1/min2/loss slots).  Chunk (r, cp) at byte r*64 + cp*16
// within an 8KB tile; cp = c ^ ((r>>1)&3).
// ---------------------------------------------------------------------------
__global__ __launch_bounds__(256) void vq_pack_kernel(
    const float* __restrict__ x, const float* __restrict__ embed,
    uint32_t* __restrict__ px, uint32_t* __restrict__ pe,
    u64* __restrict__ min1g, u64* __restrict__ min2g,
    float* __restrict__ slots) {
  const int oid  = blockIdx.x * 256 + threadIdx.x;
  const bool isX = oid < NROWS * 64;        // block-uniform split
  const int tt   = isX ? oid : oid - NROWS * 64;
  const float* src = isX ? x : embed;
  uint32_t*    dst = isX ? px : pe;

  if (oid < NROWS) { min1g[oid] = ~0ull; min2g[oid] = ~0ull; }
  if (oid < NSLOT) slots[oid] = 0.f;

  const int tile   = tt >> 9;        // (blk,kc): 512 chunks each
  const int within = tt & 511;       // = r*4 + cp
  const int blk = tile >> 4, kc = tile & 15;
  const int r   = within >> 2, cpp = within & 3;
  const int c   = cpp ^ ((r >> 1) & 3);     // source k-quarter

  const float* sp = src + (size_t)(blk * 128 + r) * D + kc * 32 + c * 8;
  const float4 v0 = *(const float4*)sp;
  const float4 v1 = *(const float4*)(sp + 4);
  uint32_t* dp = dst + (size_t)tile * 2048 + within * 4;
  *(uint4*)dp = make_uint4(pkh(v0.x, v0.y), pkh(v0.z, v0.w),
                           pkh(v1.x, v1.y), pkh(v1.z, v1.w));
}

// ---------------------------------------------------------------------------
__global__ void vq_e2_kernel(const float* __restrict__ embed,
                             float* __restrict__ e2) {
  const int w    = (blockIdx.x * blockDim.x + threadIdx.x) >> 6;
  const int lane = threadIdx.x & 63;
  const float* p = embed + (size_t)w * D + lane * 8;
  const float4 a = *(const float4*)p;
  const float4 b = *(const float4*)(p + 4);
  float s = a.x * a.x + a.y * a.y + a.z * a.z + a.w * a.w +
            b.x * b.x + b.y * b.y + b.z * b.z + b.w * b.w;
#pragma unroll
  for (int m = 32; m >= 1; m >>= 1) s += __shfl_xor(s, m, 64);
  if (lane == 0) e2[w] = s;
}

// ---------------------------------------------------------------------------
// MFMA distance kernel — R21 configuration (best verified: 219us):
// single-term fp16, 128x128 tile, 4 waves (2Mx2N, wave 64x64), double-
// buffered 2x16KB LDS, counted vmcnt(4) schedule, __launch_bounds__(256,4).
// (R22's barrier-free direct-L2 variant regressed to 249us — reverted.)
// chunkmin now written TRANSPOSED [row][chunk] so the tail reads 512B
// contiguous per row instead of 128 reads at 64KB stride.
// ---------------------------------------------------------------------------
__global__ __launch_bounds__(256, 4) void vq_mfma_kernel(
    const uint32_t* __restrict__ xp, const uint32_t* __restrict__ ep,
    const float* __restrict__ e2g, u64* __restrict__ min1g,
    u64* __restrict__ min2g, float* __restrict__ chunkmin) {
  __shared__ __align__(16) char smem[32768];
  // buffer b at b*16384: [0,8K) X | [8K,16K) E

  const int tid  = threadIdx.x;
  const int lane = tid & 63;
  const int w    = tid >> 6;          // 0..3
  const int wr   = (w >> 1) * 64;
  const int wcI  = w & 1;
  const int wc   = wcI * 64;

  // XCD swizzle (8192 % 8 == 0 -> bijective); cb fast-varying for L2 reuse.
  const int xcd = blockIdx.x & 7;
  const int id  = blockIdx.x >> 3;     // 0..1023
  const int cb  = xcd * 8 + (id & 7);  // 0..63
  const int rb  = id >> 3;             // 0..127
  const int row0 = rb * BM;
  const int c0   = cb * BN;

  const char* xtile = (const char*)xp + (size_t)rb * (NKC * TILE_B);
  const char* etile = (const char*)ep + (size_t)cb * (NKC * TILE_B);

  f32x4 acc[4][4];
#pragma unroll
  for (int i = 0; i < 4; ++i)
#pragma unroll
    for (int j = 0; j < 4; ++j) acc[i][j] = (f32x4)0.f;

  const int fr = lane & 15;
  const int cl = lane >> 4;
  const int cs = (cl ^ ((fr >> 1) & 3)) * 16;  // swizzled k-quarter byte off

#define STAGE(kc, b)                                                          \
  do {                                                                        \
    char* lb = smem + (b) * 16384 + tid * 16;                                 \
    const char* gx = xtile + (size_t)(kc) * TILE_B + tid * 16;                \
    const char* ge = etile + (size_t)(kc) * TILE_B + tid * 16;                \
    __builtin_amdgcn_global_load_lds((const as1_u32*)(const void*)gx,         \
        (as3_u32*)(void*)lb, 16, 0, 0);                                       \
    __builtin_amdgcn_global_load_lds((const as1_u32*)(const void*)(gx+4096),  \
        (as3_u32*)(void*)(lb + 4096), 16, 0, 0);                              \
    __builtin_amdgcn_global_load_lds((const as1_u32*)(const void*)ge,         \
        (as3_u32*)(void*)(lb + 8192), 16, 0, 0);                              \
    __builtin_amdgcn_global_load_lds((const as1_u32*)(const void*)(ge+4096),  \
        (as3_u32*)(void*)(lb + 12288), 16, 0, 0);                             \
  } while (0)

  STAGE(0, 0);

  int cur = 0;
  for (int t = 0; t < NKC; ++t) {
    if (t + 1 < NKC) {
      STAGE(t + 1, cur ^ 1);           // +4 loads -> 8 outstanding
      // wait ONLY for phase-t's 4 oldest; t+1's 4 remain in flight
      asm volatile("s_waitcnt vmcnt(4)" ::: "memory");
    } else {
      asm volatile("s_waitcnt vmcnt(0)" ::: "memory");
    }
    __builtin_amdgcn_s_barrier();      // all waves' t-loads now visible
    __builtin_amdgcn_sched_barrier(0);
    asm volatile("" ::: "memory");

    const char* sb = smem + cur * 16384;
    short8 bh[4];
#pragma unroll
    for (int j = 0; j < 4; ++j) {
      const int erow = wc + j * 16 + fr;
      bh[j] = *(const short8*)(sb + 8192 + erow * 64 + cs);
    }
#pragma unroll
    for (int i = 0; i < 4; ++i) {
      const int arow = wr + i * 16 + fr;
      const short8 ah = *(const short8*)(sb + arow * 64 + cs);
      __builtin_amdgcn_s_setprio(1);
#pragma unroll
      for (int j = 0; j < 4; ++j)
        acc[i][j] = __builtin_amdgcn_mfma_f32_16x16x32_f16(ah, bh[j], acc[i][j], 0, 0, 0);
      __builtin_amdgcn_s_setprio(0);
    }

    // trailing barrier: no wave may STAGE into buf `cur` while a slower
    // wave still reads it in compute(t)
    __builtin_amdgcn_s_barrier();
    __builtin_amdgcn_sched_barrier(0);
    cur ^= 1;
  }
#undef STAGE

  // ---- epilogue: per-row top-2 over this block's 128 codes ----
  float e2v[4];
#pragma unroll
  for (int j = 0; j < 4; ++j) e2v[j] = e2g[c0 + wc + j * 16 + fr];

  __syncthreads();                     // all LDS reads done; reuse smem
  u64 (*mb)[2][2] = (u64(*)[2][2])smem;  // [128 rows][2 col-waves][min1,min2]

#pragma unroll
  for (int i = 0; i < 4; ++i) {
#pragma unroll
    for (int r = 0; r < 4; ++r) {
      float v1 = 3.4e38f, v2 = 3.4e38f;
      int c1 = 0;
#pragma unroll
      for (int j = 0; j < 4; ++j) {   // codes ascend with j: lowest-idx ties
        const float s = fmaf(-2.f, acc[i][j][r], e2v[j]);
        if (s < v1) { v2 = v1; v1 = s; c1 = c0 + wc + j * 16 + fr; }
        else if (s < v2) v2 = s;
      }
      u64 p1 = ((u64)fkey(v1) << 32) | (uint32_t)c1;
      uint32_t k2 = fkey(v2);
#pragma unroll
      for (int m = 8; m >= 1; m >>= 1) {   // merge across 16-lane row-group
        const u64 o1 = __shfl_xor(p1, m, 64);
        const uint32_t o2 = __shfl_xor(k2, m, 64);
        const u64 lo_ = p1 < o1 ? p1 : o1;
        const u64 hi_ = p1 < o1 ? o1 : p1;
        uint32_t nk = k2 < o2 ? k2 : o2;
        const uint32_t hk = (uint32_t)(hi_ >> 32);
        k2 = nk < hk ? nk : hk;
        p1 = lo_;
      }
      if ((lane & 15) == 0) {
        const int lrow = wr + i * 16 + (lane >> 4) * 4 + r;
        mb[lrow][wcI][0] = p1;
        mb[lrow][wcI][1] = ((u64)k2 << 32) | 0xFFFFFFFFull;
      }
    }
  }
  __syncthreads();

  if (tid < BM) {
    const u64 m1a = mb[tid][0][0], m2a = mb[tid][0][1];
    const u64 m1b = mb[tid][1][0], m2b = mb[tid][1][1];
    // chunkmin TRANSPOSED: [row][chunk] — tail reads 512B/row contiguous.
    // Cache-line ownership stays XCD-local: line L of a row covers chunks
    // 16L..16L+15 = cb 8L..8L+7, all mapped to xcd = L by the swizzle.
    float* cm = chunkmin + (size_t)(row0 + tid) * NCH + cb * 2;
    cm[0] = unfkey((uint32_t)(m1a >> 32));
    cm[1] = unfkey((uint32_t)(m1b >> 32));
    const u64 m1 = m1a < m1b ? m1a : m1b;
    const u64 big = m1a < m1b ? m1b : m1a;
    u64 m2 = m2a < m2b ? m2a : m2b;
    m2 = m2 < big ? m2 : big;
    // lock-free global top-2 merge
    const u64 old = atomicMin(&min1g[row0 + tid], m1);
    u64 push = m1 < old ? old : m1;       // max(m1, old)
    push = m2 < push ? m2 : push;
    atomicMin(&min2g[row0 + tid], push);
  }
}

// ---------------------------------------------------------------------------
// Fused tail: flag + targeted exact rescan + gather/idx finish.  Loss goes
// to one of NSLOT fan-out slots per block (R20: 16384 same-address atomics
// serialized ~300us; R21's 2048 still ~35us serial; 32 slots ~ 1us).
// ---------------------------------------------------------------------------
__global__ __launch_bounds__(256) void vq_tail_kernel(
    const float* __restrict__ x, const float* __restrict__ embed,
    const float* __restrict__ e2g, const float* __restrict__ chunkmin,
    const u64* __restrict__ min1g, const u64* __restrict__ min2g,
    float* __restrict__ out_q, float* __restrict__ out_idx,
    float* __restrict__ slots) {
  __shared__ u64 rowres[8];
  __shared__ u64 wbest[4];
  __shared__ float lsh[4];
  const int lane = threadIdx.x & 63;
  const int wv   = threadIdx.x >> 6;
  const int row0 = blockIdx.x * 8;

  if (threadIdx.x < 8) rowres[threadIdx.x] = min1g[row0 + threadIdx.x];
  __syncthreads();

  // ---- phase A: rescan flagged rows (gap test is block-uniform) ----
  for (int r = 0; r < 8; ++r) {
    const int row = row0 + r;
    const float f1 = unfkey((uint32_t)(rowres[r] >> 32));
    const float f2 = unfkey((uint32_t)(min2g[row] >> 32));
    if (f2 - f1 >= EPS) continue;       // NaN -> rescan
    const float thr = f1 + EPS;

    const float* xpr = x + (size_t)row * D + lane * 8;
    const float4 xa = *(const float4*)xpr;
    const float4 xb = *(const float4*)(xpr + 4);

    float bv = 3.4e38f;
    int   bi = 0x7FFFFFFF;
    for (int g = wv; g < NCH; g += 4) {
      if (chunkmin[(size_t)row * NCH + g] > thr) continue;   // contiguous
      const int cbase = g * 64;
      for (int i = 0; i < 64; ++i) {
        const int c = cbase + i;
        const float* epr = embed + (size_t)c * D + lane * 8;
        const float4 ea = *(const float4*)epr;
        const float4 eb = *(const float4*)(epr + 4);
        float p = xa.x * ea.x + xa.y * ea.y + xa.z * ea.z + xa.w * ea.w +
                  xb.x * eb.x + xb.y * eb.y + xb.z * eb.z + xb.w * eb.w;
#pragma unroll
        for (int m = 32; m >= 1; m >>= 1) p += __shfl_xor(p, m, 64);
        const float s = fmaf(-2.f, p, e2g[c]);
        if (s < bv || (s == bv && c < bi)) { bv = s; bi = c; }
      }
    }
    const u64 pk = ((u64)fkey(bv) << 32) | (uint32_t)bi;
    if (lane == 0) wbest[wv] = pk;
    __syncthreads();
    if (threadIdx.x == 0) {
      u64 m = wbest[0];
#pragma unroll
      for (int q = 1; q < 4; ++q) m = wbest[q] < m ? wbest[q] : m;
      rowres[r] = m;   // exact result REPLACES approx (R10 lesson)
    }
    __syncthreads();
  }
  __syncthreads();

  // ---- phase B: finish (gather winning row, idx); loss in registers ----
  float lacc = 0.f;
  for (int rr = wv; rr < 8; rr += 4) {
    const int row = row0 + rr;
    const int idx = (int)(rowres[rr] & 0xFFFFFFFFull);
    if (lane == 0) out_idx[row] = (float)idx;

    const float* ep = embed + (size_t)idx * D + lane * 8;
    const float* xp = x + (size_t)row * D + lane * 8;
    float* qp       = out_q + (size_t)row * D + lane * 8;

    const float4 e0 = *(const float4*)ep;
    const float4 e1 = *(const float4*)(ep + 4);
    const float4 x0 = *(const float4*)xp;
    const float4 x1 = *(const float4*)(xp + 4);
    *(float4*)qp       = e0;   // x + sg(q - x) == q numerically
    *(float4*)(qp + 4) = e1;

    lacc += (e0.x - x0.x) * (e0.x - x0.x) + (e0.y - x0.y) * (e0.y - x0.y) +
            (e0.z - x0.z) * (e0.z - x0.z) + (e0.w - x0.w) * (e0.w - x0.w) +
            (e1.x - x1.x) * (e1.x - x1.x) + (e1.y - x1.y) * (e1.y - x1.y) +
            (e1.z - x1.z) * (e1.z - x1.z) + (e1.w - x1.w) * (e1.w - x1.w);
  }
  // one butterfly per wave, cross-wave via LDS, one slot atomic per block
#pragma unroll
  for (int m = 32; m >= 1; m >>= 1) lacc += __shfl_xor(lacc, m, 64);
  if (lane == 0) lsh[wv] = lacc;
  __syncthreads();
  if (threadIdx.x == 0)
    atomicAdd(&slots[blockIdx.x & (NSLOT - 1)],
              lsh[0] + lsh[1] + lsh[2] + lsh[3]);
}

// ---------------------------------------------------------------------------
// Loss finisher: one wave sums the NSLOT partials (written by atomics in
// the previous kernel; kernel-boundary coherence) and stores the scalar.
// ---------------------------------------------------------------------------
__global__ void vq_loss_kernel(const float* __restrict__ slots,
                               float* __restrict__ out_loss) {
  float s = (threadIdx.x < NSLOT) ? slots[threadIdx.x] : 0.f;
#pragma unroll
  for (int m = 32; m >= 1; m >>= 1) s += __shfl_xor(s, m, 64);
  if (threadIdx.x == 0)
    *out_loss = s * (1.f / (float)((size_t)NROWS * D));
}

// ---------------------------------------------------------------------------
extern "C" void kernel_launch(void* const* d_in, const int* in_sizes, int n_in,
                              void* d_out, int out_size, void* d_ws,
                              size_t ws_size, hipStream_t stream) {
  (void)in_sizes; (void)n_in; (void)out_size; (void)ws_size;
  const float* x     = (const float*)d_in[0];
  const float* embed = (const float*)d_in[1];

  char* ws = (char*)d_ws;
  u64*  min1    = (u64*)ws;                                  // 128 KB
  u64*  min2    = (u64*)(ws + (size_t)NROWS * 8);            // 128 KB
  float* e2     = (float*)(ws + (size_t)NROWS * 16);         // 32 KB
  float* slots  = (float*)(ws + (size_t)NROWS * 16 + NCODES * 4);  // 128 B
  float* chkmin = (float*)(ws + (1u << 20));                 // 8 MB @ 1 MB
  uint32_t* pack_x = (uint32_t*)(ws + (10u << 20));          // 16 MB @ 10 MB
  uint32_t* pack_e = (uint32_t*)(ws + (26u << 20));          // 8 MB @ 26 MB

  float* out_q    = (float*)d_out;                 // [16384][512]
  float* out_idx  = out_q + (size_t)NROWS * D;     // [16384] as float
  float* out_loss = out_idx + NROWS;               // [1]

  // 5 dispatches
  vq_pack_kernel<<<(NROWS + NCODES) * 64 / 256, 256, 0, stream>>>(
      x, embed, pack_x, pack_e, min1, min2, slots);
  vq_e2_kernel<<<NCODES / 4, 256, 0, stream>>>(embed, e2);
  vq_mfma_kernel<<<NBLK, 256, 0, stream>>>(pack_x, pack_e, e2, min1, min2,
                                           chkmin);
  vq_tail_kernel<<<TCB, 256, 0, stream>>>(x, embed, e2, chkmin, min1, min2,
                                          out_q, out_idx, slots);
  vq_loss_kernel<<<1, 64, 0, stream>>>(slots, out_loss);
}

// Round 24
// 307.473 us; speedup vs baseline: 1.2216x; 1.1589x over previous
//
#include <hip/hip_runtime.h>
#include <hip/hip_fp16.h>
#include <cstdint>
#include <cstddef>

#define D       512
#define NROWS   16384
#define NCODES  8192
#define BM      128
#define BN      128
#define NKC     16              // phases: BK=32 each
#define NBLK    8192            // (16384/128)*(8192/128)
#define EPS     0.2f            // 2B; fp16 1-term err std ~0.02 -> ~10 sigma
#define TCB     2048            // tail kernel blocks (8 rows each)
#define TILE_B  8192            // packed fp16 tile per (blk128, ktile32)
#define NCH     128             // 64-code chunks per row
#define NSLOT   32              // loss fan-out slots

typedef __attribute__((ext_vector_type(8))) short short8;  // 8 fp16
typedef __attribute__((ext_vector_type(4))) float f32x4;
typedef unsigned long long u64;
typedef __attribute__((address_space(3))) uint32_t as3_u32;
typedef __attribute__((address_space(1))) uint32_t as1_u32;

// order-preserving fp32 <-> u32 key
__device__ __forceinline__ uint32_t fkey(float f) {
  uint32_t u = __float_as_uint(f);
  return (u & 0x80000000u) ? ~u : (u | 0x80000000u);
}
__device__ __forceinline__ float unfkey(uint32_t k) {
  uint32_t u = (k & 0x80000000u) ? (k & 0x7FFFFFFFu) : ~k;
  return __uint_as_float(u);
}
__device__ __forceinline__ uint32_t pkh(float a, float b) {  // 2xfp16 RN pack
  const uint32_t ua = (uint32_t)__half_as_ushort(__float2half(a));
  const uint32_t ub = (uint32_t)__half_as_ushort(__float2half(b));
  return ua | (ub << 16);
}

// ---------------------------------------------------------------------------
// Pre-pack fp32 -> fp16, OUTPUT-address-ordered, tile-kc layout, plus fused
// workspace init (min1/min2/loss slots).  Chunk (r, cp) at byte r*64 + cp*16
// within an 8KB tile; cp = c ^ ((r>>1)&3).
// ---------------------------------------------------------------------------
__global__ __launch_bounds__(256) void vq_pack_kernel(
    const float* __restrict__ x, const float* __restrict__ embed,
    uint32_t* __restrict__ px, uint32_t* __restrict__ pe,
    u64* __restrict__ min1g, u64* __restrict__ min2g,
    float* __restrict__ slots) {
  const int oid  = blockIdx.x * 256 + threadIdx.x;
  const bool isX = oid < NROWS * 64;        // block-uniform split
  const int tt   = isX ? oid : oid - NROWS * 64;
  const float* src = isX ? x : embed;
  uint32_t*    dst = isX ? px : pe;

  if (oid < NROWS) { min1g[oid] = ~0ull; min2g[oid] = ~0ull; }
  if (oid < NSLOT) slots[oid] = 0.f;

  const int tile   = tt >> 9;        // (blk,kc): 512 chunks each
  const int within = tt & 511;       // = r*4 + cp
  const int blk = tile >> 4, kc = tile & 15;
  const int r   = within >> 2, cpp = within & 3;
  const int c   = cpp ^ ((r >> 1) & 3);     // source k-quarter

  const float* sp = src + (size_t)(blk * 128 + r) * D + kc * 32 + c * 8;
  const float4 v0 = *(const float4*)sp;
  const float4 v1 = *(const float4*)(sp + 4);
  uint32_t* dp = dst + (size_t)tile * 2048 + within * 4;
  *(uint4*)dp = make_uint4(pkh(v0.x, v0.y), pkh(v0.z, v0.w),
                           pkh(v1.x, v1.y), pkh(v1.z, v1.w));
}

// ---------------------------------------------------------------------------
__global__ void vq_e2_kernel(const float* __restrict__ embed,
                             float* __restrict__ e2) {
  const int w    = (blockIdx.x * blockDim.x + threadIdx.x) >> 6;
  const int lane = threadIdx.x & 63;
  const float* p = embed + (size_t)w * D + lane * 8;
  const float4 a = *(const float4*)p;
  const float4 b = *(const float4*)(p + 4);
  float s = a.x * a.x + a.y * a.y + a.z * a.z + a.w * a.w +
            b.x * b.x + b.y * b.y + b.z * b.z + b.w * b.w;
#pragma unroll
  for (int m = 32; m >= 1; m >>= 1) s += __shfl_xor(s, m, 64);
  if (lane == 0) e2[w] = s;
}

// ---------------------------------------------------------------------------
// MFMA distance kernel — R21 configuration, FROZEN (verified best: 219us;
// R22 restructure regressed).  Single-term fp16, 128x128 tile, 4 waves
// (2Mx2N, wave 64x64), double-buffered 2x16KB LDS, counted vmcnt(4)
// schedule, __launch_bounds__(256,4).  chunkmin written [row][chunk].
// ---------------------------------------------------------------------------
__global__ __launch_bounds__(256, 4) void vq_mfma_kernel(
    const uint32_t* __restrict__ xp, const uint32_t* __restrict__ ep,
    const float* __restrict__ e2g, u64* __restrict__ min1g,
    u64* __restrict__ min2g, float* __restrict__ chunkmin) {
  __shared__ __align__(16) char smem[32768];
  // buffer b at b*16384: [0,8K) X | [8K,16K) E

  const int tid  = threadIdx.x;
  const int lane = tid & 63;
  const int w    = tid >> 6;          // 0..3
  const int wr   = (w >> 1) * 64;
  const int wcI  = w & 1;
  const int wc   = wcI * 64;

  // XCD swizzle (8192 % 8 == 0 -> bijective); cb fast-varying for L2 reuse.
  const int xcd = blockIdx.x & 7;
  const int id  = blockIdx.x >> 3;     // 0..1023
  const int cb  = xcd * 8 + (id & 7);  // 0..63
  const int rb  = id >> 3;             // 0..127
  const int row0 = rb * BM;
  const int c0   = cb * BN;

  const char* xtile = (const char*)xp + (size_t)rb * (NKC * TILE_B);
  const char* etile = (const char*)ep + (size_t)cb * (NKC * TILE_B);

  f32x4 acc[4][4];
#pragma unroll
  for (int i = 0; i < 4; ++i)
#pragma unroll
    for (int j = 0; j < 4; ++j) acc[i][j] = (f32x4)0.f;

  const int fr = lane & 15;
  const int cl = lane >> 4;
  const int cs = (cl ^ ((fr >> 1) & 3)) * 16;  // swizzled k-quarter byte off

#define STAGE(kc, b)                                                          \
  do {                                                                        \
    char* lb = smem + (b) * 16384 + tid * 16;                                 \
    const char* gx = xtile + (size_t)(kc) * TILE_B + tid * 16;                \
    const char* ge = etile + (size_t)(kc) * TILE_B + tid * 16;                \
    __builtin_amdgcn_global_load_lds((const as1_u32*)(const void*)gx,         \
        (as3_u32*)(void*)lb, 16, 0, 0);                                       \
    __builtin_amdgcn_global_load_lds((const as1_u32*)(const void*)(gx+4096),  \
        (as3_u32*)(void*)(lb + 4096), 16, 0, 0);                              \
    __builtin_amdgcn_global_load_lds((const as1_u32*)(const void*)ge,         \
        (as3_u32*)(void*)(lb + 8192), 16, 0, 0);                              \
    __builtin_amdgcn_global_load_lds((const as1_u32*)(const void*)(ge+4096),  \
        (as3_u32*)(void*)(lb + 12288), 16, 0, 0);                             \
  } while (0)

  STAGE(0, 0);

  int cur = 0;
  for (int t = 0; t < NKC; ++t) {
    if (t + 1 < NKC) {
      STAGE(t + 1, cur ^ 1);           // +4 loads -> 8 outstanding
      // wait ONLY for phase-t's 4 oldest; t+1's 4 remain in flight
      asm volatile("s_waitcnt vmcnt(4)" ::: "memory");
    } else {
      asm volatile("s_waitcnt vmcnt(0)" ::: "memory");
    }
    __builtin_amdgcn_s_barrier();      // all waves' t-loads now visible
    __builtin_amdgcn_sched_barrier(0);
    asm volatile("" ::: "memory");

    const char* sb = smem + cur * 16384;
    short8 bh[4];
#pragma unroll
    for (int j = 0; j < 4; ++j) {
      const int erow = wc + j * 16 + fr;
      bh[j] = *(const short8*)(sb + 8192 + erow * 64 + cs);
    }
#pragma unroll
    for (int i = 0; i < 4; ++i) {
      const int arow = wr + i * 16 + fr;
      const short8 ah = *(const short8*)(sb + arow * 64 + cs);
      __builtin_amdgcn_s_setprio(1);
#pragma unroll
      for (int j = 0; j < 4; ++j)
        acc[i][j] = __builtin_amdgcn_mfma_f32_16x16x32_f16(ah, bh[j], acc[i][j], 0, 0, 0);
      __builtin_amdgcn_s_setprio(0);
    }

    // trailing barrier: no wave may STAGE into buf `cur` while a slower
    // wave still reads it in compute(t)
    __builtin_amdgcn_s_barrier();
    __builtin_amdgcn_sched_barrier(0);
    cur ^= 1;
  }
#undef STAGE

  // ---- epilogue: per-row top-2 over this block's 128 codes ----
  float e2v[4];
#pragma unroll
  for (int j = 0; j < 4; ++j) e2v[j] = e2g[c0 + wc + j * 16 + fr];

  __syncthreads();                     // all LDS reads done; reuse smem
  u64 (*mb)[2][2] = (u64(*)[2][2])smem;  // [128 rows][2 col-waves][min1,min2]

#pragma unroll
  for (int i = 0; i < 4; ++i) {
#pragma unroll
    for (int r = 0; r < 4; ++r) {
      float v1 = 3.4e38f, v2 = 3.4e38f;
      int c1 = 0;
#pragma unroll
      for (int j = 0; j < 4; ++j) {   // codes ascend with j: lowest-idx ties
        const float s = fmaf(-2.f, acc[i][j][r], e2v[j]);
        if (s < v1) { v2 = v1; v1 = s; c1 = c0 + wc + j * 16 + fr; }
        else if (s < v2) v2 = s;
      }
      u64 p1 = ((u64)fkey(v1) << 32) | (uint32_t)c1;
      uint32_t k2 = fkey(v2);
#pragma unroll
      for (int m = 8; m >= 1; m >>= 1) {   // merge across 16-lane row-group
        const u64 o1 = __shfl_xor(p1, m, 64);
        const uint32_t o2 = __shfl_xor(k2, m, 64);
        const u64 lo_ = p1 < o1 ? p1 : o1;
        const u64 hi_ = p1 < o1 ? o1 : p1;
        uint32_t nk = k2 < o2 ? k2 : o2;
        const uint32_t hk = (uint32_t)(hi_ >> 32);
        k2 = nk < hk ? nk : hk;
        p1 = lo_;
      }
      if ((lane & 15) == 0) {
        const int lrow = wr + i * 16 + (lane >> 4) * 4 + r;
        mb[lrow][wcI][0] = p1;
        mb[lrow][wcI][1] = ((u64)k2 << 32) | 0xFFFFFFFFull;
      }
    }
  }
  __syncthreads();

  if (tid < BM) {
    const u64 m1a = mb[tid][0][0], m2a = mb[tid][0][1];
    const u64 m1b = mb[tid][1][0], m2b = mb[tid][1][1];
    // chunkmin [row][chunk]: tail reads 512B/row contiguous; line L of a
    // row covers cb 8L..8L+7 = exactly xcd L under the swizzle (XCD-local).
    float* cm = chunkmin + (size_t)(row0 + tid) * NCH + cb * 2;
    cm[0] = unfkey((uint32_t)(m1a >> 32));
    cm[1] = unfkey((uint32_t)(m1b >> 32));
    const u64 m1 = m1a < m1b ? m1a : m1b;
    const u64 big = m1a < m1b ? m1b : m1a;
    u64 m2 = m2a < m2b ? m2a : m2b;
    m2 = m2 < big ? m2 : big;
    // lock-free global top-2 merge
    const u64 old = atomicMin(&min1g[row0 + tid], m1);
    u64 push = m1 < old ? old : m1;       // max(m1, old)
    push = m2 < push ? m2 : push;
    atomicMin(&min2g[row0 + tid], push);
  }
}

// ---------------------------------------------------------------------------
// Fused tail: flag + targeted exact rescan + gather/idx finish.
// Rescan now processes EIGHT codes per iteration: 8 loads in flight, then
// 6 butterfly rounds of 8 interleaved shfl+add.  (R23 audit: one-code-at-a-
// time made each code ~350cyc of serial cross-lane latency — a 64-code
// chunk cost ~10us on a single wave.)  Tie-break: compare in ascending
// code order after reduction.
// ---------------------------------------------------------------------------
__global__ __launch_bounds__(256) void vq_tail_kernel(
    const float* __restrict__ x, const float* __restrict__ embed,
    const float* __restrict__ e2g, const float* __restrict__ chunkmin,
    const u64* __restrict__ min1g, const u64* __restrict__ min2g,
    float* __restrict__ out_q, float* __restrict__ out_idx,
    float* __restrict__ slots) {
  __shared__ u64 rowres[8];
  __shared__ u64 wbest[4];
  __shared__ float lsh[4];
  const int lane = threadIdx.x & 63;
  const int wv   = threadIdx.x >> 6;
  const int row0 = blockIdx.x * 8;

  if (threadIdx.x < 8) rowres[threadIdx.x] = min1g[row0 + threadIdx.x];
  __syncthreads();

  // ---- phase A: rescan flagged rows (gap test is block-uniform) ----
  for (int r = 0; r < 8; ++r) {
    const int row = row0 + r;
    const float f1 = unfkey((uint32_t)(rowres[r] >> 32));
    const float f2 = unfkey((uint32_t)(min2g[row] >> 32));
    if (f2 - f1 >= EPS) continue;       // NaN -> rescan
    const float thr = f1 + EPS;

    const float* xpr = x + (size_t)row * D + lane * 8;
    const float4 xa = *(const float4*)xpr;
    const float4 xb = *(const float4*)(xpr + 4);

    float bv = 3.4e38f;
    int   bi = 0x7FFFFFFF;
    for (int g = wv; g < NCH; g += 4) {
      if (chunkmin[(size_t)row * NCH + g] > thr) continue;   // contiguous
      const int cbase = g * 64;
      for (int i = 0; i < 64; i += 8) {
        float pv[8];
#pragma unroll
        for (int u = 0; u < 8; ++u) {   // 8 loads in flight
          const float* epr = embed + (size_t)(cbase + i + u) * D + lane * 8;
          const float4 ea = *(const float4*)epr;
          const float4 eb = *(const float4*)(epr + 4);
          pv[u] = xa.x * ea.x + xa.y * ea.y + xa.z * ea.z + xa.w * ea.w +
                  xb.x * eb.x + xb.y * eb.y + xb.z * eb.z + xb.w * eb.w;
        }
#pragma unroll
        for (int m = 32; m >= 1; m >>= 1) {   // 8 interleaved butterflies
#pragma unroll
          for (int u = 0; u < 8; ++u) pv[u] += __shfl_xor(pv[u], m, 64);
        }
#pragma unroll
        for (int u = 0; u < 8; ++u) {   // ascending order: lowest-idx ties
          const int c = cbase + i + u;
          const float s = fmaf(-2.f, pv[u], e2g[c]);
          if (s < bv || (s == bv && c < bi)) { bv = s; bi = c; }
        }
      }
    }
    const u64 pk = ((u64)fkey(bv) << 32) | (uint32_t)bi;
    if (lane == 0) wbest[wv] = pk;
    __syncthreads();
    if (threadIdx.x == 0) {
      u64 m = wbest[0];
#pragma unroll
      for (int q = 1; q < 4; ++q) m = wbest[q] < m ? wbest[q] : m;
      rowres[r] = m;   // exact result REPLACES approx (R10 lesson)
    }
    __syncthreads();
  }
  __syncthreads();

  // ---- phase B: finish (gather winning row, idx); loss in registers ----
  float lacc = 0.f;
  for (int rr = wv; rr < 8; rr += 4) {
    const int row = row0 + rr;
    const int idx = (int)(rowres[rr] & 0xFFFFFFFFull);
    if (lane == 0) out_idx[row] = (float)idx;

    const float* ep = embed + (size_t)idx * D + lane * 8;
    const float* xp = x + (size_t)row * D + lane * 8;
    float* qp       = out_q + (size_t)row * D + lane * 8;

    const float4 e0 = *(const float4*)ep;
    const float4 e1 = *(const float4*)(ep + 4);
    const float4 x0 = *(const float4*)xp;
    const float4 x1 = *(const float4*)(xp + 4);
    *(float4*)qp       = e0;   // x + sg(q - x) == q numerically
    *(float4*)(qp + 4) = e1;

    lacc += (e0.x - x0.x) * (e0.x - x0.x) + (e0.y - x0.y) * (e0.y - x0.y) +
            (e0.z - x0.z) * (e0.z - x0.z) + (e0.w - x0.w) * (e0.w - x0.w) +
            (e1.x - x1.x) * (e1.x - x1.x) + (e1.y - x1.y) * (e1.y - x1.y) +
            (e1.z - x1.z) * (e1.z - x1.z) + (e1.w - x1.w) * (e1.w - x1.w);
  }
  // one butterfly per wave, cross-wave via LDS, one slot atomic per block
#pragma unroll
  for (int m = 32; m >= 1; m >>= 1) lacc += __shfl_xor(lacc, m, 64);
  if (lane == 0) lsh[wv] = lacc;
  __syncthreads();
  if (threadIdx.x == 0)
    atomicAdd(&slots[blockIdx.x & (NSLOT - 1)],
              lsh[0] + lsh[1] + lsh[2] + lsh[3]);
}

// ---------------------------------------------------------------------------
// Loss finisher: one wave sums the NSLOT partials and stores the scalar.
// ---------------------------------------------------------------------------
__global__ void vq_loss_kernel(const float* __restrict__ slots,
                               float* __restrict__ out_loss) {
  float s = (threadIdx.x < NSLOT) ? slots[threadIdx.x] : 0.f;
#pragma unroll
  for (int m = 32; m >= 1; m >>= 1) s += __shfl_xor(s, m, 64);
  if (threadIdx.x == 0)
    *out_loss = s * (1.f / (float)((size_t)NROWS * D));
}

// ---------------------------------------------------------------------------
extern "C" void kernel_launch(void* const* d_in, const int* in_sizes, int n_in,
                              void* d_out, int out_size, void* d_ws,
                              size_t ws_size, hipStream_t stream) {
  (void)in_sizes; (void)n_in; (void)out_size; (void)ws_size;
  const float* x     = (const float*)d_in[0];
  const float* embed = (const float*)d_in[1];

  char* ws = (char*)d_ws;
  u64*  min1    = (u64*)ws;                                  // 128 KB
  u64*  min2    = (u64*)(ws + (size_t)NROWS * 8);            // 128 KB
  float* e2     = (float*)(ws + (size_t)NROWS * 16);         // 32 KB
  float* slots  = (float*)(ws + (size_t)NROWS * 16 + NCODES * 4);  // 128 B
  float* chkmin = (float*)(ws + (1u << 20));                 // 8 MB @ 1 MB
  uint32_t* pack_x = (uint32_t*)(ws + (10u << 20));          // 16 MB @ 10 MB
  uint32_t* pack_e = (uint32_t*)(ws + (26u << 20));          // 8 MB @ 26 MB

  float* out_q    = (float*)d_out;                 // [16384][512]
  float* out_idx  = out_q + (size_t)NROWS * D;     // [16384] as float
  float* out_loss = out_idx + NROWS;               // [1]

  // 5 dispatches
  vq_pack_kernel<<<(NROWS + NCODES) * 64 / 256, 256, 0, stream>>>(
      x, embed, pack_x, pack_e, min1, min2, slots);
  vq_e2_kernel<<<NCODES / 4, 256, 0, stream>>>(embed, e2);
  vq_mfma_kernel<<<NBLK, 256, 0, stream>>>(pack_x, pack_e, e2, min1, min2,
                                           chkmin);
  vq_tail_kernel<<<TCB, 256, 0, stream>>>(x, embed, e2, chkmin, min1, min2,
                                          out_q, out_idx, slots);
  vq_loss_kernel<<<1, 64, 0, stream>>>(slots, out_loss);
}

// Round 25
// 300.355 us; speedup vs baseline: 1.2505x; 1.0237x over previous
//
#include <hip/hip_runtime.h>
#include <hip/hip_fp16.h>
#include <cstdint>
#include <cstddef>

#define D       512
#define NROWS   16384
#define NCODES  8192
#define BM      128
#define BN      256             // R25: doubled N per block (amortize phase cost)
#define NKC     16              // phases: BK=32 each
#define NBLK    4096            // (16384/128)*(8192/256)
#define EPS     0.2f
#define TCB     2048            // tail kernel blocks (8 rows each)
#define TILE_B  8192            // packed fp16 tile per (blk128, ktile32)
#define NCH     128             // 64-code chunks per row
#define NSLOT   32              // loss fan-out slots

typedef __attribute__((ext_vector_type(8))) short short8;  // 8 fp16
typedef __attribute__((ext_vector_type(4))) float f32x4;
typedef unsigned long long u64;
typedef __attribute__((address_space(3))) uint32_t as3_u32;
typedef __attribute__((address_space(1))) uint32_t as1_u32;

// order-preserving fp32 <-> u32 key
__device__ __forceinline__ uint32_t fkey(float f) {
  uint32_t u = __float_as_uint(f);
  return (u & 0x80000000u) ? ~u : (u | 0x80000000u);
}
__device__ __forceinline__ float unfkey(uint32_t k) {
  uint32_t u = (k & 0x80000000u) ? (k & 0x7FFFFFFFu) : ~k;
  return __uint_as_float(u);
}
__device__ __forceinline__ uint32_t pkh(float a, float b) {  // 2xfp16 RN pack
  const uint32_t ua = (uint32_t)__half_as_ushort(__float2half(a));
  const uint32_t ub = (uint32_t)__half_as_ushort(__float2half(b));
  return ua | (ub << 16);
}

// ---------------------------------------------------------------------------
// Pre-pack fp32 -> fp16, OUTPUT-address-ordered, tile-kc layout, plus fused
// workspace init.  Chunk (r, cp) at byte r*64 + cp*16; cp = c ^ ((r>>1)&3).
// ---------------------------------------------------------------------------
__global__ __launch_bounds__(256) void vq_pack_kernel(
    const float* __restrict__ x, const float* __restrict__ embed,
    uint32_t* __restrict__ px, uint32_t* __restrict__ pe,
    u64* __restrict__ min1g, u64* __restrict__ min2g,
    float* __restrict__ slots) {
  const int oid  = blockIdx.x * 256 + threadIdx.x;
  const bool isX = oid < NROWS * 64;        // block-uniform split
  const int tt   = isX ? oid : oid - NROWS * 64;
  const float* src = isX ? x : embed;
  uint32_t*    dst = isX ? px : pe;

  if (oid < NROWS) { min1g[oid] = ~0ull; min2g[oid] = ~0ull; }
  if (oid < NSLOT) slots[oid] = 0.f;

  const int tile   = tt >> 9;        // (blk,kc): 512 chunks each
  const int within = tt & 511;       // = r*4 + cp
  const int blk = tile >> 4, kc = tile & 15;
  const int r   = within >> 2, cpp = within & 3;
  const int c   = cpp ^ ((r >> 1) & 3);     // source k-quarter

  const float* sp = src + (size_t)(blk * 128 + r) * D + kc * 32 + c * 8;
  const float4 v0 = *(const float4*)sp;
  const float4 v1 = *(const float4*)(sp + 4);
  uint32_t* dp = dst + (size_t)tile * 2048 + within * 4;
  *(uint4*)dp = make_uint4(pkh(v0.x, v0.y), pkh(v0.z, v0.w),
                           pkh(v1.x, v1.y), pkh(v1.z, v1.w));
}

// ---------------------------------------------------------------------------
__global__ void vq_e2_kernel(const float* __restrict__ embed,
                             float* __restrict__ e2) {
  const int w    = (blockIdx.x * blockDim.x + threadIdx.x) >> 6;
  const int lane = threadIdx.x & 63;
  const float* p = embed + (size_t)w * D + lane * 8;
  const float4 a = *(const float4*)p;
  const float4 b = *(const float4*)(p + 4);
  float s = a.x * a.x + a.y * a.y + a.z * a.z + a.w * a.w +
            b.x * b.x + b.y * b.y + b.z * b.z + b.w * b.w;
#pragma unroll
  for (int m = 32; m >= 1; m >>= 1) s += __shfl_xor(s, m, 64);
  if (lane == 0) e2[w] = s;
}

// ---------------------------------------------------------------------------
// MFMA distance kernel, R25: 128x256 tile, 512 thr (8 waves 2Mx4N, per-wave
// tile 64x64 unchanged), double-buffered 2x24KB LDS (48KB -> 2 blocks/CU =
// 16 waves/CU), counted-vmcnt schedule.  Rationale: R13-R24 showed a
// ~3400cyc/phase fixed cost vs 64 block-MFMA; BN=256 gives 128 MFMA/phase
// per block (2x amortization) at equal VGPR budget (launch_bounds(512,4)
// -> 128 regs/wave, same as R21's achieved fit).
// STAGE = THREE 16B loads/thread (8KB X + 16KB E over 512 thr) -> steady
// state s_waitcnt vmcnt(3)  [N = loads-per-stage x stages-ahead = 3x1].
// ---------------------------------------------------------------------------
__global__ __launch_bounds__(512, 4) void vq_mfma_kernel(
    const uint32_t* __restrict__ xp, const uint32_t* __restrict__ ep,
    const float* __restrict__ e2g, u64* __restrict__ min1g,
    u64* __restrict__ min2g, float* __restrict__ chunkmin) {
  __shared__ __align__(16) char smem[49152];
  // buffer b at b*24576: [0,8K) X | [8K,24K) E (two 8KB code-tiles)

  const int tid  = threadIdx.x;
  const int lane = tid & 63;
  const int w    = tid >> 6;          // 0..7
  const int wr   = (w >> 2) * 64;     // 0 / 64
  const int wcI  = w & 3;             // 0..3
  const int wc   = wcI * 64;

  // XCD swizzle (4096 % 8 == 0 -> bijective); cb fast-varying for L2 reuse
  // (4 cbs x 256KB packed-e per XCD = 1MB, L2-resident).
  const int xcd = blockIdx.x & 7;
  const int id  = blockIdx.x >> 3;     // 0..511
  const int cb  = xcd * 4 + (id & 3);  // 0..31
  const int rb  = id >> 2;             // 0..127
  const int row0 = rb * BM;
  const int c0   = cb * BN;

  const char* xtile  = (const char*)xp + (size_t)rb * (NKC * TILE_B);
  const char* etile0 = (const char*)ep + (size_t)(2 * cb) * (NKC * TILE_B);
  const char* etile1 = etile0 + (size_t)(NKC * TILE_B);

  f32x4 acc[4][4];
#pragma unroll
  for (int i = 0; i < 4; ++i)
#pragma unroll
    for (int j = 0; j < 4; ++j) acc[i][j] = (f32x4)0.f;

  const int fr = lane & 15;
  const int cl = lane >> 4;
  const int cs = (cl ^ ((fr >> 1) & 3)) * 16;  // swizzled k-quarter byte off

#define STAGE(kc, b)                                                          \
  do {                                                                        \
    char* lb = smem + (b) * 24576;                                            \
    __builtin_amdgcn_global_load_lds(                                         \
        (const as1_u32*)(const void*)(xtile + (size_t)(kc) * TILE_B + tid * 16), \
        (as3_u32*)(void*)(lb + tid * 16), 16, 0, 0);                          \
    __builtin_amdgcn_global_load_lds(                                         \
        (const as1_u32*)(const void*)(etile0 + (size_t)(kc) * TILE_B + tid * 16), \
        (as3_u32*)(void*)(lb + 8192 + tid * 16), 16, 0, 0);                   \
    __builtin_amdgcn_global_load_lds(                                         \
        (const as1_u32*)(const void*)(etile1 + (size_t)(kc) * TILE_B + tid * 16), \
        (as3_u32*)(void*)(lb + 16384 + tid * 16), 16, 0, 0);                  \
  } while (0)

  STAGE(0, 0);

  int cur = 0;
  for (int t = 0; t < NKC; ++t) {
    if (t + 1 < NKC) {
      STAGE(t + 1, cur ^ 1);           // +3 loads -> 6 outstanding
      // wait ONLY for phase-t's 3 oldest; t+1's 3 remain in flight
      asm volatile("s_waitcnt vmcnt(3)" ::: "memory");
    } else {
      asm volatile("s_waitcnt vmcnt(0)" ::: "memory");
    }
    __builtin_amdgcn_s_barrier();      // all waves' t-loads now visible
    __builtin_amdgcn_sched_barrier(0);
    asm volatile("" ::: "memory");

    const char* sb = smem + cur * 24576;
    short8 bh[4];
#pragma unroll
    for (int j = 0; j < 4; ++j) {
      const int erow = wc + j * 16 + fr;     // 0..255
      bh[j] = *(const short8*)(sb + 8192 + (erow >> 7) * 8192 +
                               (erow & 127) * 64 + cs);
    }
#pragma unroll
    for (int i = 0; i < 4; ++i) {
      const int arow = wr + i * 16 + fr;     // 0..127
      const short8 ah = *(const short8*)(sb + arow * 64 + cs);
      __builtin_amdgcn_s_setprio(1);
#pragma unroll
      for (int j = 0; j < 4; ++j)
        acc[i][j] = __builtin_amdgcn_mfma_f32_16x16x32_f16(ah, bh[j], acc[i][j], 0, 0, 0);
      __builtin_amdgcn_s_setprio(0);
    }

    // trailing barrier: no wave may STAGE into buf `cur` while a slower
    // wave still reads it in compute(t)
    __builtin_amdgcn_s_barrier();
    __builtin_amdgcn_sched_barrier(0);
    cur ^= 1;
  }
#undef STAGE

  // ---- epilogue: per-row top-2 over this block's 256 codes ----
  float e2v[4];
#pragma unroll
  for (int j = 0; j < 4; ++j) e2v[j] = e2g[c0 + wc + j * 16 + fr];

  __syncthreads();                       // all LDS reads done; reuse smem
  u64 (*mb)[4][2] = (u64(*)[4][2])smem;  // [128 rows][4 col-waves][min1,min2]

#pragma unroll
  for (int i = 0; i < 4; ++i) {
#pragma unroll
    for (int r = 0; r < 4; ++r) {
      float v1 = 3.4e38f, v2 = 3.4e38f;
      int c1 = 0;
#pragma unroll
      for (int j = 0; j < 4; ++j) {   // codes ascend with j: lowest-idx ties
        const float s = fmaf(-2.f, acc[i][j][r], e2v[j]);
        if (s < v1) { v2 = v1; v1 = s; c1 = c0 + wc + j * 16 + fr; }
        else if (s < v2) v2 = s;
      }
      u64 p1 = ((u64)fkey(v1) << 32) | (uint32_t)c1;
      uint32_t k2 = fkey(v2);
#pragma unroll
      for (int m = 8; m >= 1; m >>= 1) {   // merge across 16-lane row-group
        const u64 o1 = __shfl_xor(p1, m, 64);
        const uint32_t o2 = __shfl_xor(k2, m, 64);
        const u64 lo_ = p1 < o1 ? p1 : o1;
        const u64 hi_ = p1 < o1 ? o1 : p1;
        uint32_t nk = k2 < o2 ? k2 : o2;
        const uint32_t hk = (uint32_t)(hi_ >> 32);
        k2 = nk < hk ? nk : hk;
        p1 = lo_;
      }
      if ((lane & 15) == 0) {
        const int lrow = wr + i * 16 + (lane >> 4) * 4 + r;
        mb[lrow][wcI][0] = p1;
        mb[lrow][wcI][1] = ((u64)k2 << 32) | 0xFFFFFFFFull;
      }
    }
  }
  __syncthreads();

  if (tid < BM) {
    u64 m1 = mb[tid][0][0], m2 = mb[tid][0][1];
    // chunkmin [row][chunk], 64-code chunks; this block owns chunks
    // cb*4..cb*4+3.  Line L of a row covers cb 4L..4L+3 = exactly xcd L
    // under the swizzle (XCD-local writes).
    float* cm = chunkmin + (size_t)(row0 + tid) * NCH + cb * 4;
    cm[0] = unfkey((uint32_t)(mb[tid][0][0] >> 32));
#pragma unroll
    for (int q = 1; q < 4; ++q) {
      const u64 a1 = mb[tid][q][0], a2 = mb[tid][q][1];
      cm[q] = unfkey((uint32_t)(a1 >> 32));
      const u64 nm1 = m1 < a1 ? m1 : a1;
      const u64 big = m1 < a1 ? a1 : m1;
      u64 nm2 = m2 < a2 ? m2 : a2;
      nm2 = nm2 < big ? nm2 : big;
      m1 = nm1; m2 = nm2;
    }
    // lock-free global top-2 merge
    const u64 old = atomicMin(&min1g[row0 + tid], m1);
    u64 push = m1 < old ? old : m1;       // max(m1, old)
    push = m2 < push ? m2 : push;
    atomicMin(&min2g[row0 + tid], push);
  }
}

// ---------------------------------------------------------------------------
// Fused tail (R24-frozen): flag + targeted exact rescan (8-code ILP) +
// gather/idx finish; loss via NSLOT fan-out slots.
// ---------------------------------------------------------------------------
__global__ __launch_bounds__(256) void vq_tail_kernel(
    const float* __restrict__ x, const float* __restrict__ embed,
    const float* __restrict__ e2g, const float* __restrict__ chunkmin,
    const u64* __restrict__ min1g, const u64* __restrict__ min2g,
    float* __restrict__ out_q, float* __restrict__ out_idx,
    float* __restrict__ slots) {
  __shared__ u64 rowres[8];
  __shared__ u64 wbest[4];
  __shared__ float lsh[4];
  const int lane = threadIdx.x & 63;
  const int wv   = threadIdx.x >> 6;
  const int row0 = blockIdx.x * 8;

  if (threadIdx.x < 8) rowres[threadIdx.x] = min1g[row0 + threadIdx.x];
  __syncthreads();

  // ---- phase A: rescan flagged rows (gap test is block-uniform) ----
  for (int r = 0; r < 8; ++r) {
    const int row = row0 + r;
    const float f1 = unfkey((uint32_t)(rowres[r] >> 32));
    const float f2 = unfkey((uint32_t)(min2g[row] >> 32));
    if (f2 - f1 >= EPS) continue;       // NaN -> rescan
    const float thr = f1 + EPS;

    const float* xpr = x + (size_t)row * D + lane * 8;
    const float4 xa = *(const float4*)xpr;
    const float4 xb = *(const float4*)(xpr + 4);

    float bv = 3.4e38f;
    int   bi = 0x7FFFFFFF;
    for (int g = wv; g < NCH; g += 4) {
      if (chunkmin[(size_t)row * NCH + g] > thr) continue;   // contiguous
      const int cbase = g * 64;
      for (int i = 0; i < 64; i += 8) {
        float pv[8];
#pragma unroll
        for (int u = 0; u < 8; ++u) {   // 8 loads in flight
          const float* epr = embed + (size_t)(cbase + i + u) * D + lane * 8;
          const float4 ea = *(const float4*)epr;
          const float4 eb = *(const float4*)(epr + 4);
          pv[u] = xa.x * ea.x + xa.y * ea.y + xa.z * ea.z + xa.w * ea.w +
                  xb.x * eb.x + xb.y * eb.y + xb.z * eb.z + xb.w * eb.w;
        }
#pragma unroll
        for (int m = 32; m >= 1; m >>= 1) {   // 8 interleaved butterflies
#pragma unroll
          for (int u = 0; u < 8; ++u) pv[u] += __shfl_xor(pv[u], m, 64);
        }
#pragma unroll
        for (int u = 0; u < 8; ++u) {   // ascending order: lowest-idx ties
          const int c = cbase + i + u;
          const float s = fmaf(-2.f, pv[u], e2g[c]);
          if (s < bv || (s == bv && c < bi)) { bv = s; bi = c; }
        }
      }
    }
    const u64 pk = ((u64)fkey(bv) << 32) | (uint32_t)bi;
    if (lane == 0) wbest[wv] = pk;
    __syncthreads();
    if (threadIdx.x == 0) {
      u64 m = wbest[0];
#pragma unroll
      for (int q = 1; q < 4; ++q) m = wbest[q] < m ? wbest[q] : m;
      rowres[r] = m;   // exact result REPLACES approx (R10 lesson)
    }
    __syncthreads();
  }
  __syncthreads();

  // ---- phase B: finish (gather winning row, idx); loss in registers ----
  float lacc = 0.f;
  for (int rr = wv; rr < 8; rr += 4) {
    const int row = row0 + rr;
    const int idx = (int)(rowres[rr] & 0xFFFFFFFFull);
    if (lane == 0) out_idx[row] = (float)idx;

    const float* ep = embed + (size_t)idx * D + lane * 8;
    const float* xp = x + (size_t)row * D + lane * 8;
    float* qp       = out_q + (size_t)row * D + lane * 8;

    const float4 e0 = *(const float4*)ep;
    const float4 e1 = *(const float4*)(ep + 4);
    const float4 x0 = *(const float4*)xp;
    const float4 x1 = *(const float4*)(xp + 4);
    *(float4*)qp       = e0;   // x + sg(q - x) == q numerically
    *(float4*)(qp + 4) = e1;

    lacc += (e0.x - x0.x) * (e0.x - x0.x) + (e0.y - x0.y) * (e0.y - x0.y) +
            (e0.z - x0.z) * (e0.z - x0.z) + (e0.w - x0.w) * (e0.w - x0.w) +
            (e1.x - x1.x) * (e1.x - x1.x) + (e1.y - x1.y) * (e1.y - x1.y) +
            (e1.z - x1.z) * (e1.z - x1.z) + (e1.w - x1.w) * (e1.w - x1.w);
  }
  // one butterfly per wave, cross-wave via LDS, one slot atomic per block
#pragma unroll
  for (int m = 32; m >= 1; m >>= 1) lacc += __shfl_xor(lacc, m, 64);
  if (lane == 0) lsh[wv] = lacc;
  __syncthreads();
  if (threadIdx.x == 0)
    atomicAdd(&slots[blockIdx.x & (NSLOT - 1)],
              lsh[0] + lsh[1] + lsh[2] + lsh[3]);
}

// ---------------------------------------------------------------------------
__global__ void vq_loss_kernel(const float* __restrict__ slots,
                               float* __restrict__ out_loss) {
  float s = (threadIdx.x < NSLOT) ? slots[threadIdx.x] : 0.f;
#pragma unroll
  for (int m = 32; m >= 1; m >>= 1) s += __shfl_xor(s, m, 64);
  if (threadIdx.x == 0)
    *out_loss = s * (1.f / (float)((size_t)NROWS * D));
}

// ---------------------------------------------------------------------------
extern "C" void kernel_launch(void* const* d_in, const int* in_sizes, int n_in,
                              void* d_out, int out_size, void* d_ws,
                              size_t ws_size, hipStream_t stream) {
  (void)in_sizes; (void)n_in; (void)out_size; (void)ws_size;
  const float* x     = (const float*)d_in[0];
  const float* embed = (const float*)d_in[1];

  char* ws = (char*)d_ws;
  u64*  min1    = (u64*)ws;                                  // 128 KB
  u64*  min2    = (u64*)(ws + (size_t)NROWS * 8);            // 128 KB
  float* e2     = (float*)(ws + (size_t)NROWS * 16);         // 32 KB
  float* slots  = (float*)(ws + (size_t)NROWS * 16 + NCODES * 4);  // 128 B
  float* chkmin = (float*)(ws + (1u << 20));                 // 8 MB @ 1 MB
  uint32_t* pack_x = (uint32_t*)(ws + (10u << 20));          // 16 MB @ 10 MB
  uint32_t* pack_e = (uint32_t*)(ws + (26u << 20));          // 8 MB @ 26 MB

  float* out_q    = (float*)d_out;                 // [16384][512]
  float* out_idx  = out_q + (size_t)NROWS * D;     // [16384] as float
  float* out_loss = out_idx + NROWS;               // [1]

  // 5 dispatches
  vq_pack_kernel<<<(NROWS + NCODES) * 64 / 256, 256, 0, stream>>>(
      x, embed, pack_x, pack_e, min1, min2, slots);
  vq_e2_kernel<<<NCODES / 4, 256, 0, stream>>>(embed, e2);
  vq_mfma_kernel<<<NBLK, 512, 0, stream>>>(pack_x, pack_e, e2, min1, min2,
                                           chkmin);
  vq_tail_kernel<<<TCB, 256, 0, stream>>>(x, embed, e2, chkmin, min1, min2,
                                          out_q, out_idx, slots);
  vq_loss_kernel<<<1, 64, 0, stream>>>(slots, out_loss);
}

// Round 26
// 277.645 us; speedup vs baseline: 1.3528x; 1.0818x over previous
//
#include <hip/hip_runtime.h>
#include <hip/hip_fp16.h>
#include <cstdint>
#include <cstddef>

#define D       512
#define NROWS   16384
#define NCODES  8192
#define BM      128
#define BN      256
#define NKC     16              // phases: BK=32 each
#define NBLK    4096            // (16384/128)*(8192/256)
#define EPS     0.2f
#define TCB     2048            // tail kernel blocks (8 rows each)
#define TILE_B  8192            // packed fp16 tile per (blk128, ktile32)
#define NCH     128             // 64-code chunks per row
#define NSLOT   32              // loss fan-out slots

typedef __attribute__((ext_vector_type(8))) short short8;  // 8 fp16
typedef __attribute__((ext_vector_type(4))) float f32x4;
typedef unsigned long long u64;
typedef __attribute__((address_space(3))) uint32_t as3_u32;
typedef __attribute__((address_space(1))) uint32_t as1_u32;

// order-preserving fp32 <-> u32 key
__device__ __forceinline__ uint32_t fkey(float f) {
  uint32_t u = __float_as_uint(f);
  return (u & 0x80000000u) ? ~u : (u | 0x80000000u);
}
__device__ __forceinline__ float unfkey(uint32_t k) {
  uint32_t u = (k & 0x80000000u) ? (k & 0x7FFFFFFFu) : ~k;
  return __uint_as_float(u);
}
__device__ __forceinline__ uint32_t pkh(float a, float b) {  // 2xfp16 RN pack
  const uint32_t ua = (uint32_t)__half_as_ushort(__float2half(a));
  const uint32_t ub = (uint32_t)__half_as_ushort(__float2half(b));
  return ua | (ub << 16);
}

// ---------------------------------------------------------------------------
// Pre-pack fp32 -> fp16, OUTPUT-address-ordered, tile-kc layout, plus fused
// workspace init.  Chunk (r, cp) at byte r*64 + cp*16; cp = c ^ ((r>>1)&3).
// ---------------------------------------------------------------------------
__global__ __launch_bounds__(256) void vq_pack_kernel(
    const float* __restrict__ x, const float* __restrict__ embed,
    uint32_t* __restrict__ px, uint32_t* __restrict__ pe,
    u64* __restrict__ min1g, u64* __restrict__ min2g,
    float* __restrict__ slots) {
  const int oid  = blockIdx.x * 256 + threadIdx.x;
  const bool isX = oid < NROWS * 64;        // block-uniform split
  const int tt   = isX ? oid : oid - NROWS * 64;
  const float* src = isX ? x : embed;
  uint32_t*    dst = isX ? px : pe;

  if (oid < NROWS) { min1g[oid] = ~0ull; min2g[oid] = ~0ull; }
  if (oid < NSLOT) slots[oid] = 0.f;

  const int tile   = tt >> 9;        // (blk,kc): 512 chunks each
  const int within = tt & 511;       // = r*4 + cp
  const int blk = tile >> 4, kc = tile & 15;
  const int r   = within >> 2, cpp = within & 3;
  const int c   = cpp ^ ((r >> 1) & 3);     // source k-quarter

  const float* sp = src + (size_t)(blk * 128 + r) * D + kc * 32 + c * 8;
  const float4 v0 = *(const float4*)sp;
  const float4 v1 = *(const float4*)(sp + 4);
  uint32_t* dp = dst + (size_t)tile * 2048 + within * 4;
  *(uint4*)dp = make_uint4(pkh(v0.x, v0.y), pkh(v0.z, v0.w),
                           pkh(v1.x, v1.y), pkh(v1.z, v1.w));
}

// ---------------------------------------------------------------------------
__global__ void vq_e2_kernel(const float* __restrict__ embed,
                             float* __restrict__ e2) {
  const int w    = (blockIdx.x * blockDim.x + threadIdx.x) >> 6;
  const int lane = threadIdx.x & 63;
  const float* p = embed + (size_t)w * D + lane * 8;
  const float4 a = *(const float4*)p;
  const float4 b = *(const float4*)(p + 4);
  float s = a.x * a.x + a.y * a.y + a.z * a.z + a.w * a.w +
            b.x * b.x + b.y * b.y + b.z * b.z + b.w * b.w;
#pragma unroll
  for (int m = 32; m >= 1; m >>= 1) s += __shfl_xor(s, m, 64);
  if (lane == 0) e2[w] = s;
}

// ---------------------------------------------------------------------------
// MFMA distance kernel, R26: HYBRID operand paths.
//   E (B-operand): staged via global_load_lds into double-buffered 2x16KB
//     LDS, counted-vmcnt barrier cadence (verified R21/R25 schedule).
//   X (A-operand): NO LDS — frags prefetched one phase ahead, global->VGPR
//     (per-wave A working set 16KB/CU-phase is L1-resident; address path
//     correctness-validated in R22).
// Rationale: R25 counter model puts the LDS pipe at ~47% of the phase wall
// (128 frag reads + 48KB writes per CU-phase); removing A halves reads and
// cuts writes 1/3 -> ~1024cyc.  vmcnt derivation (count actual loads, R18
// lesson): per iter issue = 4 A-loads + 2 DMA; at the check, required-
// retired = DMA(t) (oldest 2) -> wait vmcnt(6).  A registers double-set
// (aCur/aNxt, explicit copy — rule #20: no dynamic register indexing).
// ---------------------------------------------------------------------------
__global__ __launch_bounds__(512, 4) void vq_mfma_kernel(
    const uint32_t* __restrict__ xp, const uint32_t* __restrict__ ep,
    const float* __restrict__ e2g, u64* __restrict__ min1g,
    u64* __restrict__ min2g, float* __restrict__ chunkmin) {
  __shared__ __align__(16) char smem[32768];
  // buffer b at b*16384: two 8KB E code-tiles

  const int tid  = threadIdx.x;
  const int lane = tid & 63;
  const int w    = tid >> 6;          // 0..7
  const int wr   = (w >> 2) * 64;     // 0 / 64
  const int wcI  = w & 3;             // 0..3
  const int wc   = wcI * 64;

  // XCD swizzle (4096 % 8 == 0 -> bijective); cb fast-varying for L2 reuse.
  const int xcd = blockIdx.x & 7;
  const int id  = blockIdx.x >> 3;     // 0..511
  const int cb  = xcd * 4 + (id & 3);  // 0..31
  const int rb  = id >> 2;             // 0..127
  const int row0 = rb * BM;
  const int c0   = cb * BN;

  const char* xtile  = (const char*)xp + (size_t)rb * (NKC * TILE_B);
  const char* etile0 = (const char*)ep + (size_t)(2 * cb) * (NKC * TILE_B);
  const char* etile1 = etile0 + (size_t)(NKC * TILE_B);

  f32x4 acc[4][4];
#pragma unroll
  for (int i = 0; i < 4; ++i)
#pragma unroll
    for (int j = 0; j < 4; ++j) acc[i][j] = (f32x4)0.f;

  const int fr = lane & 15;
  const int cl = lane >> 4;
  const int cs = (cl ^ ((fr >> 1) & 3)) * 16;  // swizzled k-quarter byte off

#define STAGE_E(kc, b)                                                        \
  do {                                                                        \
    char* lb = smem + (b) * 16384;                                            \
    __builtin_amdgcn_global_load_lds(                                         \
        (const as1_u32*)(const void*)(etile0 + (size_t)(kc) * TILE_B + tid * 16), \
        (as3_u32*)(void*)(lb + tid * 16), 16, 0, 0);                          \
    __builtin_amdgcn_global_load_lds(                                         \
        (const as1_u32*)(const void*)(etile1 + (size_t)(kc) * TILE_B + tid * 16), \
        (as3_u32*)(void*)(lb + 8192 + tid * 16), 16, 0, 0);                   \
  } while (0)

#define LOAD_A(kc, dst)                                                       \
  do {                                                                        \
    _Pragma("unroll") for (int i = 0; i < 4; ++i)                             \
      dst[i] = *(const short8*)(xtile + (size_t)(kc) * TILE_B +               \
                                (wr + i * 16 + fr) * 64 + cs);                \
  } while (0)

  short8 aCur[4], aNxt[4];
  LOAD_A(0, aCur);
  STAGE_E(0, 0);

  int cur = 0;
  for (int t = 0; t < NKC; ++t) {
    if (t + 1 < NKC) {
      LOAD_A(t + 1, aNxt);             // 4 global loads (A prefetch)
      STAGE_E(t + 1, cur ^ 1);         // 2 DMA loads
      // outstanding: DMA(t)[2 oldest] + A(t+1)[4] + DMA(t+1)[2] = 8;
      // wait DMA(t) retired -> vmcnt <= 6 (in-order retirement, m135)
      asm volatile("s_waitcnt vmcnt(6)" ::: "memory");
    } else {
      asm volatile("s_waitcnt vmcnt(0)" ::: "memory");
    }
    __builtin_amdgcn_s_barrier();      // all waves' E(t) now visible
    __builtin_amdgcn_sched_barrier(0);
    asm volatile("" ::: "memory");

    const char* sb = smem + cur * 16384;
    short8 bh[4];
#pragma unroll
    for (int j = 0; j < 4; ++j) {
      const int erow = wc + j * 16 + fr;     // 0..255
      bh[j] = *(const short8*)(sb + (erow >> 7) * 8192 +
                               (erow & 127) * 64 + cs);
    }
#pragma unroll
    for (int i = 0; i < 4; ++i) {
      __builtin_amdgcn_s_setprio(1);
#pragma unroll
      for (int j = 0; j < 4; ++j)
        acc[i][j] = __builtin_amdgcn_mfma_f32_16x16x32_f16(aCur[i], bh[j], acc[i][j], 0, 0, 0);
      __builtin_amdgcn_s_setprio(0);
    }

    // trailing barrier: no wave may STAGE_E into buf `cur` while a slower
    // wave still reads it in compute(t)
    __builtin_amdgcn_s_barrier();
    __builtin_amdgcn_sched_barrier(0);
    cur ^= 1;
#pragma unroll
    for (int i = 0; i < 4; ++i) aCur[i] = aNxt[i];
  }
#undef STAGE_E
#undef LOAD_A

  // ---- epilogue: per-row top-2 over this block's 256 codes ----
  float e2v[4];
#pragma unroll
  for (int j = 0; j < 4; ++j) e2v[j] = e2g[c0 + wc + j * 16 + fr];

  __syncthreads();                       // all LDS reads done; reuse smem
  u64 (*mb)[4][2] = (u64(*)[4][2])smem;  // [128 rows][4 col-waves][min1,min2]

#pragma unroll
  for (int i = 0; i < 4; ++i) {
#pragma unroll
    for (int r = 0; r < 4; ++r) {
      float v1 = 3.4e38f, v2 = 3.4e38f;
      int c1 = 0;
#pragma unroll
      for (int j = 0; j < 4; ++j) {   // codes ascend with j: lowest-idx ties
        const float s = fmaf(-2.f, acc[i][j][r], e2v[j]);
        if (s < v1) { v2 = v1; v1 = s; c1 = c0 + wc + j * 16 + fr; }
        else if (s < v2) v2 = s;
      }
      u64 p1 = ((u64)fkey(v1) << 32) | (uint32_t)c1;
      uint32_t k2 = fkey(v2);
#pragma unroll
      for (int m = 8; m >= 1; m >>= 1) {   // merge across 16-lane row-group
        const u64 o1 = __shfl_xor(p1, m, 64);
        const uint32_t o2 = __shfl_xor(k2, m, 64);
        const u64 lo_ = p1 < o1 ? p1 : o1;
        const u64 hi_ = p1 < o1 ? o1 : p1;
        uint32_t nk = k2 < o2 ? k2 : o2;
        const uint32_t hk = (uint32_t)(hi_ >> 32);
        k2 = nk < hk ? nk : hk;
        p1 = lo_;
      }
      if ((lane & 15) == 0) {
        const int lrow = wr + i * 16 + (lane >> 4) * 4 + r;
        mb[lrow][wcI][0] = p1;
        mb[lrow][wcI][1] = ((u64)k2 << 32) | 0xFFFFFFFFull;
      }
    }
  }
  __syncthreads();

  if (tid < BM) {
    u64 m1 = mb[tid][0][0], m2 = mb[tid][0][1];
    // chunkmin [row][chunk]; this block owns chunks cb*4..cb*4+3 (XCD-local
    // lines under the swizzle).
    float* cm = chunkmin + (size_t)(row0 + tid) * NCH + cb * 4;
    cm[0] = unfkey((uint32_t)(mb[tid][0][0] >> 32));
#pragma unroll
    for (int q = 1; q < 4; ++q) {
      const u64 a1 = mb[tid][q][0], a2 = mb[tid][q][1];
      cm[q] = unfkey((uint32_t)(a1 >> 32));
      const u64 nm1 = m1 < a1 ? m1 : a1;
      const u64 big = m1 < a1 ? a1 : m1;
      u64 nm2 = m2 < a2 ? m2 : a2;
      nm2 = nm2 < big ? nm2 : big;
      m1 = nm1; m2 = nm2;
    }
    // lock-free global top-2 merge
    const u64 old = atomicMin(&min1g[row0 + tid], m1);
    u64 push = m1 < old ? old : m1;       // max(m1, old)
    push = m2 < push ? m2 : push;
    atomicMin(&min2g[row0 + tid], push);
  }
}

// ---------------------------------------------------------------------------
// Fused tail (R24-frozen): flag + targeted exact rescan (8-code ILP) +
// gather/idx finish; loss via NSLOT fan-out slots.
// ---------------------------------------------------------------------------
__global__ __launch_bounds__(256) void vq_tail_kernel(
    const float* __restrict__ x, const float* __restrict__ embed,
    const float* __restrict__ e2g, const float* __restrict__ chunkmin,
    const u64* __restrict__ min1g, const u64* __restrict__ min2g,
    float* __restrict__ out_q, float* __restrict__ out_idx,
    float* __restrict__ slots) {
  __shared__ u64 rowres[8];
  __shared__ u64 wbest[4];
  __shared__ float lsh[4];
  const int lane = threadIdx.x & 63;
  const int wv   = threadIdx.x >> 6;
  const int row0 = blockIdx.x * 8;

  if (threadIdx.x < 8) rowres[threadIdx.x] = min1g[row0 + threadIdx.x];
  __syncthreads();

  // ---- phase A: rescan flagged rows (gap test is block-uniform) ----
  for (int r = 0; r < 8; ++r) {
    const int row = row0 + r;
    const float f1 = unfkey((uint32_t)(rowres[r] >> 32));
    const float f2 = unfkey((uint32_t)(min2g[row] >> 32));
    if (f2 - f1 >= EPS) continue;       // NaN -> rescan
    const float thr = f1 + EPS;

    const float* xpr = x + (size_t)row * D + lane * 8;
    const float4 xa = *(const float4*)xpr;
    const float4 xb = *(const float4*)(xpr + 4);

    float bv = 3.4e38f;
    int   bi = 0x7FFFFFFF;
    for (int g = wv; g < NCH; g += 4) {
      if (chunkmin[(size_t)row * NCH + g] > thr) continue;   // contiguous
      const int cbase = g * 64;
      for (int i = 0; i < 64; i += 8) {
        float pv[8];
#pragma unroll
        for (int u = 0; u < 8; ++u) {   // 8 loads in flight
          const float* epr = embed + (size_t)(cbase + i + u) * D + lane * 8;
          const float4 ea = *(const float4*)epr;
          const float4 eb = *(const float4*)(epr + 4);
          pv[u] = xa.x * ea.x + xa.y * ea.y + xa.z * ea.z + xa.w * ea.w +
                  xb.x * eb.x + xb.y * eb.y + xb.z * eb.z + xb.w * eb.w;
        }
#pragma unroll
        for (int m = 32; m >= 1; m >>= 1) {   // 8 interleaved butterflies
#pragma unroll
          for (int u = 0; u < 8; ++u) pv[u] += __shfl_xor(pv[u], m, 64);
        }
#pragma unroll
        for (int u = 0; u < 8; ++u) {   // ascending order: lowest-idx ties
          const int c = cbase + i + u;
          const float s = fmaf(-2.f, pv[u], e2g[c]);
          if (s < bv || (s == bv && c < bi)) { bv = s; bi = c; }
        }
      }
    }
    const u64 pk = ((u64)fkey(bv) << 32) | (uint32_t)bi;
    if (lane == 0) wbest[wv] = pk;
    __syncthreads();
    if (threadIdx.x == 0) {
      u64 m = wbest[0];
#pragma unroll
      for (int q = 1; q < 4; ++q) m = wbest[q] < m ? wbest[q] : m;
      rowres[r] = m;   // exact result REPLACES approx (R10 lesson)
    }
    __syncthreads();
  }
  __syncthreads();

  // ---- phase B: finish (gather winning row, idx); loss in registers ----
  float lacc = 0.f;
  for (int rr = wv; rr < 8; rr += 4) {
    const int row = row0 + rr;
    const int idx = (int)(rowres[rr] & 0xFFFFFFFFull);
    if (lane == 0) out_idx[row] = (float)idx;

    const float* ep = embed + (size_t)idx * D + lane * 8;
    const float* xp = x + (size_t)row * D + lane * 8;
    float* qp       = out_q + (size_t)row * D + lane * 8;

    const float4 e0 = *(const float4*)ep;
    const float4 e1 = *(const float4*)(ep + 4);
    const float4 x0 = *(const float4*)xp;
    const float4 x1 = *(const float4*)(xp + 4);
    *(float4*)qp       = e0;   // x + sg(q - x) == q numerically
    *(float4*)(qp + 4) = e1;

    lacc += (e0.x - x0.x) * (e0.x - x0.x) + (e0.y - x0.y) * (e0.y - x0.y) +
            (e0.z - x0.z) * (e0.z - x0.z) + (e0.w - x0.w) * (e0.w - x0.w) +
            (e1.x - x1.x) * (e1.x - x1.x) + (e1.y - x1.y) * (e1.y - x1.y) +
            (e1.z - x1.z) * (e1.z - x1.z) + (e1.w - x1.w) * (e1.w - x1.w);
  }
  // one butterfly per wave, cross-wave via LDS, one slot atomic per block
#pragma unroll
  for (int m = 32; m >= 1; m >>= 1) lacc += __shfl_xor(lacc, m, 64);
  if (lane == 0) lsh[wv] = lacc;
  __syncthreads();
  if (threadIdx.x == 0)
    atomicAdd(&slots[blockIdx.x & (NSLOT - 1)],
              lsh[0] + lsh[1] + lsh[2] + lsh[3]);
}

// ---------------------------------------------------------------------------
__global__ void vq_loss_kernel(const float* __restrict__ slots,
                               float* __restrict__ out_loss) {
  float s = (threadIdx.x < NSLOT) ? slots[threadIdx.x] : 0.f;
#pragma unroll
  for (int m = 32; m >= 1; m >>= 1) s += __shfl_xor(s, m, 64);
  if (threadIdx.x == 0)
    *out_loss = s * (1.f / (float)((size_t)NROWS * D));
}

// ---------------------------------------------------------------------------
extern "C" void kernel_launch(void* const* d_in, const int* in_sizes, int n_in,
                              void* d_out, int out_size, void* d_ws,
                              size_t ws_size, hipStream_t stream) {
  (void)in_sizes; (void)n_in; (void)out_size; (void)ws_size;
  const float* x     = (const float*)d_in[0];
  const float* embed = (const float*)d_in[1];

  char* ws = (char*)d_ws;
  u64*  min1    = (u64*)ws;                                  // 128 KB
  u64*  min2    = (u64*)(ws + (size_t)NROWS * 8);            // 128 KB
  float* e2     = (float*)(ws + (size_t)NROWS * 16);         // 32 KB
  float* slots  = (float*)(ws + (size_t)NROWS * 16 + NCODES * 4);  // 128 B
  float* chkmin = (float*)(ws + (1u << 20));                 // 8 MB @ 1 MB
  uint32_t* pack_x = (uint32_t*)(ws + (10u << 20));          // 16 MB @ 10 MB
  uint32_t* pack_e = (uint32_t*)(ws + (26u << 20));          // 8 MB @ 26 MB

  float* out_q    = (float*)d_out;                 // [16384][512]
  float* out_idx  = out_q + (size_t)NROWS * D;     // [16384] as float
  float* out_loss = out_idx + NROWS;               // [1]

  // 5 dispatches
  vq_pack_kernel<<<(NROWS + NCODES) * 64 / 256, 256, 0, stream>>>(
      x, embed, pack_x, pack_e, min1, min2, slots);
  vq_e2_kernel<<<NCODES / 4, 256, 0, stream>>>(embed, e2);
  vq_mfma_kernel<<<NBLK, 512, 0, stream>>>(pack_x, pack_e, e2, min1, min2,
                                           chkmin);
  vq_tail_kernel<<<TCB, 256, 0, stream>>>(x, embed, e2, chkmin, min1, min2,
                                          out_q, out_idx, slots);
  vq_loss_kernel<<<1, 64, 0, stream>>>(slots, out_loss);
}